// Round 2
// baseline (114.676 us; speedup 1.0000x reference)
//
#include <hip/hip_runtime.h>

#define ALPHA 0.2f
#define B 4
#define D 128
#define K 512

// ---------------- Path A (ws_size >= 1 MB) ----------------
// K1: R^T[b][c][k] = sum_d x[b,d,k] * W2[d][c]   (W2 = lin_w[D:])
// Coalesced: lanes span c for the W2 read; store is a column of R^T (scattered
// dwords, 16 MB total L2 write traffic — cheap).
__global__ __launch_bounds__(128) void gat_rt(const float* __restrict__ x,
                                              const float* __restrict__ lin_w,
                                              float* __restrict__ Rt) {
  const int k = blockIdx.x, b = blockIdx.y, t = threadIdx.x;  // t = c
  __shared__ float sx[D];
  sx[t] = x[((size_t)b * D + t) * K + k];
  __syncthreads();
  const float* W2 = lin_w + (size_t)D * D + t;
  float acc = 0.f;
#pragma unroll 8
  for (int d = 0; d < D; ++d) acc = fmaf(sx[d], W2[(size_t)d * D], acc);
  Rt[((size_t)b * D + t) * K + k] = acc;
}

// K2: per (b,i): compute L[i,:] in-block, e[j] from R^T (coalesced over j),
// softmax, agg with interleaved float4 chunks, sigmoid + residual.
__global__ __launch_bounds__(512) void gat_attn(
    const float* __restrict__ x, const float* __restrict__ lin_w,
    const float* __restrict__ lin_b, const float* __restrict__ a,
    const float* __restrict__ bias, const float* __restrict__ Rt,
    float* __restrict__ out) {
  const int i = blockIdx.x, b = blockIdx.y, t = threadIdx.x;  // 0..511
  __shared__ float sxi[D], sLi[D], sa[D];
  __shared__ float lpart[4 * D];
  __shared__ float sattn[K], spart[K];
  __shared__ float sred[8];

  if (t < D) {
    sxi[t] = x[((size_t)b * D + t) * K + i];
    sa[t] = a[t];
  }
  __syncthreads();

  // ---- L[i,c]: 4-way split over d ----
  {
    const int c = t & (D - 1), q = t >> 7;  // q in 0..3
    float acc = 0.f;
    const float* W1 = lin_w + c;
#pragma unroll 8
    for (int d = q * 32; d < q * 32 + 32; ++d)
      acc = fmaf(sxi[d], W1[(size_t)d * D], acc);
    lpart[q * D + c] = acc;
  }
  __syncthreads();
  if (t < D)
    sLi[t] = lin_b[t] + lpart[t] + lpart[D + t] + lpart[2 * D + t] +
             lpart[3 * D + t];
  __syncthreads();

  // ---- e[j], j = t; R^T column read is lane-coalesced ----
  const float* Rcol = Rt + (size_t)b * D * K + t;
  float e = 0.f;
#pragma unroll 8
  for (int d = 0; d < D; ++d) {
    const float pre = sLi[d] + Rcol[(size_t)d * K];
    e = fmaf(sa[d], pre > 0.f ? pre : ALPHA * pre, e);
  }
  e += bias[(size_t)i * K + t];

  // ---- softmax over 512 (8 waves) ----
  float m = e;
#pragma unroll
  for (int off = 32; off > 0; off >>= 1) m = fmaxf(m, __shfl_xor(m, off, 64));
  if ((t & 63) == 0) sred[t >> 6] = m;
  __syncthreads();
  m = sred[0];
#pragma unroll
  for (int w = 1; w < 8; ++w) m = fmaxf(m, sred[w]);
  const float ev = __expf(e - m);
  float s = ev;
#pragma unroll
  for (int off = 32; off > 0; off >>= 1) s += __shfl_xor(s, off, 64);
  __syncthreads();  // all done reading sred (max)
  if ((t & 63) == 0) sred[t >> 6] = s;
  __syncthreads();
  s = 0.f;
#pragma unroll
  for (int w = 0; w < 8; ++w) s += sred[w];
  sattn[t] = ev * (1.f / s);
  __syncthreads();

  // ---- agg: thread (d = t>>2, c = t&3), INTERLEAVED float4 chunks so
  // lanes of one d-group touch one 64B line per iteration ----
  const int d = t >> 2, c = t & 3;
  const float4* X4 = (const float4*)(x + ((size_t)b * D + d) * K);
  const float4* A4 = (const float4*)sattn;
  float p = 0.f;
#pragma unroll 4
  for (int q = 0; q < K / 16; ++q) {
    const int idx = c + 4 * q;
    float4 xv = X4[idx], av = A4[idx];
    p = fmaf(av.x, xv.x, p);
    p = fmaf(av.y, xv.y, p);
    p = fmaf(av.z, xv.z, p);
    p = fmaf(av.w, xv.w, p);
  }
  spart[t] = p;
  __syncthreads();
  if (t < D) {
    const float agg =
        spart[4 * t] + spart[4 * t + 1] + spart[4 * t + 2] + spart[4 * t + 3];
    const float sg = 1.f / (1.f + __expf(-agg));
    out[((size_t)b * D + t) * K + i] = sg + sxi[t];
  }
}

// ---------------- Fallback (ws too small): fused, ws-free ----------------
// One block per (b,i). Recomputes R in j-tiles of 64 from an LDS-staged
// xt tile; W2 reads are wave-uniform (scalar loads).
__global__ __launch_bounds__(512) void gat_fused(
    const float* __restrict__ x, const float* __restrict__ lin_w,
    const float* __restrict__ lin_b, const float* __restrict__ a,
    const float* __restrict__ bias, float* __restrict__ out) {
  const int i = blockIdx.x, b = blockIdx.y, t = threadIdx.x;
  __shared__ float sxi[D], sLi[D], sa[D];
  __shared__ float lpart[4 * D];
  __shared__ float xtT[D * 64];  // [d][jj] for current j-tile
  __shared__ float epars[8 * 64];
  __shared__ float se[K];
  __shared__ float sattn[K], spart[K];
  __shared__ float sred[8];

  if (t < D) {
    sxi[t] = x[((size_t)b * D + t) * K + i];
    sa[t] = a[t];
  }
  __syncthreads();
  {
    const int c = t & (D - 1), q = t >> 7;
    float acc = 0.f;
    const float* W1 = lin_w + c;
#pragma unroll 8
    for (int d = q * 32; d < q * 32 + 32; ++d)
      acc = fmaf(sxi[d], W1[(size_t)d * D], acc);
    lpart[q * D + c] = acc;
  }
  __syncthreads();
  if (t < D)
    sLi[t] = lin_b[t] + lpart[t] + lpart[D + t] + lpart[2 * D + t] +
             lpart[3 * D + t];
  __syncthreads();

  for (int jt = 0; jt < K / 64; ++jt) {
    const int j0 = jt * 64;
    for (int idx = t; idx < D * 64; idx += 512)
      xtT[idx] = x[((size_t)b * D + (idx >> 6)) * K + j0 + (idx & 63)];
    __syncthreads();
    const int jj = t & 63, g = t >> 6, dp0 = g * 16;
    float accv[16];
#pragma unroll
    for (int v = 0; v < 16; ++v) accv[v] = 0.f;
    for (int dc = 0; dc < D; dc += 16) {
      float xv[16];
#pragma unroll
      for (int u = 0; u < 16; ++u) xv[u] = xtT[(dc + u) * 64 + jj];
#pragma unroll
      for (int u = 0; u < 16; ++u) {
        const float* W2r = lin_w + (size_t)(D + dc + u) * D + dp0;
#pragma unroll
        for (int v = 0; v < 16; ++v) accv[v] = fmaf(xv[u], W2r[v], accv[v]);
      }
    }
    float ep = 0.f;
#pragma unroll
    for (int v = 0; v < 16; ++v) {
      const float pre = sLi[dp0 + v] + accv[v];
      ep = fmaf(sa[dp0 + v], pre > 0.f ? pre : ALPHA * pre, ep);
    }
    epars[g * 64 + jj] = ep;
    __syncthreads();
    if (t < 64) {
      float esum = bias[(size_t)i * K + j0 + t];
#pragma unroll
      for (int g2 = 0; g2 < 8; ++g2) esum += epars[g2 * 64 + t];
      se[j0 + t] = esum;
    }
    __syncthreads();
  }

  float e = se[t];
  float m = e;
#pragma unroll
  for (int off = 32; off > 0; off >>= 1) m = fmaxf(m, __shfl_xor(m, off, 64));
  if ((t & 63) == 0) sred[t >> 6] = m;
  __syncthreads();
  m = sred[0];
#pragma unroll
  for (int w = 1; w < 8; ++w) m = fmaxf(m, sred[w]);
  const float ev = __expf(e - m);
  float s = ev;
#pragma unroll
  for (int off = 32; off > 0; off >>= 1) s += __shfl_xor(s, off, 64);
  __syncthreads();
  if ((t & 63) == 0) sred[t >> 6] = s;
  __syncthreads();
  s = 0.f;
#pragma unroll
  for (int w = 0; w < 8; ++w) s += sred[w];
  sattn[t] = ev * (1.f / s);
  __syncthreads();

  const int d = t >> 2, c = t & 3;
  const float4* X4 = (const float4*)(x + ((size_t)b * D + d) * K);
  const float4* A4 = (const float4*)sattn;
  float p = 0.f;
#pragma unroll 4
  for (int q = 0; q < K / 16; ++q) {
    const int idx = c + 4 * q;
    float4 xv = X4[idx], av = A4[idx];
    p = fmaf(av.x, xv.x, p);
    p = fmaf(av.y, xv.y, p);
    p = fmaf(av.z, xv.z, p);
    p = fmaf(av.w, xv.w, p);
  }
  spart[t] = p;
  __syncthreads();
  if (t < D) {
    const float agg =
        spart[4 * t] + spart[4 * t + 1] + spart[4 * t + 2] + spart[4 * t + 3];
    const float sg = 1.f / (1.f + __expf(-agg));
    out[((size_t)b * D + t) * K + i] = sg + sxi[t];
  }
}

extern "C" void kernel_launch(void* const* d_in, const int* in_sizes, int n_in,
                              void* d_out, int out_size, void* d_ws,
                              size_t ws_size, hipStream_t stream) {
  const float* x = (const float*)d_in[0];
  const float* lin_w = (const float*)d_in[1];
  const float* lin_b = (const float*)d_in[2];
  const float* a = (const float*)d_in[3];
  const float* bias = (const float*)d_in[4];
  float* out = (float*)d_out;

  const size_t need = (size_t)B * K * D * sizeof(float);  // 1 MB
  dim3 g(K, B);
  if (ws_size >= need && d_ws != nullptr) {
    float* Rt = (float*)d_ws;
    gat_rt<<<g, 128, 0, stream>>>(x, lin_w, Rt);
    gat_attn<<<g, 512, 0, stream>>>(x, lin_w, lin_b, a, bias, Rt, out);
  } else {
    gat_fused<<<g, 512, 0, stream>>>(x, lin_w, lin_b, a, bias, out);
  }
}

// Round 3
// 98.471 us; speedup vs baseline: 1.1646x; 1.1646x over previous
//
#include <hip/hip_runtime.h>

#define B 4
#define D 128
#define K 512
#define TI 8

// ---------------- K1: Rhat^T[b][e][j] = 0.8*|a_e| * sum_c x[b][c][j]*W2[c][e]
// Grid (K/128, D/8, B), 128 threads. W2 8-col slab staged in LDS; x reads
// lane-coalesced along j; 8 FMA per 4B x-load.
__global__ __launch_bounds__(128) void gat_rhat(const float* __restrict__ x,
                                                const float* __restrict__ lin_w,
                                                const float* __restrict__ a,
                                                float* __restrict__ Rt) {
  const int j0 = blockIdx.x * 128;
  const int e0 = blockIdx.y * 8;
  const int b = blockIdx.z;
  const int t = threadIdx.x;
  __shared__ float sw2[D][8];
#pragma unroll
  for (int u = 0; u < 8; ++u) {
    const int idx = u * 128 + t;
    sw2[idx >> 3][idx & 7] =
        lin_w[(size_t)(D + (idx >> 3)) * D + e0 + (idx & 7)];
  }
  __syncthreads();
  float acc[8];
#pragma unroll
  for (int u = 0; u < 8; ++u) acc[u] = 0.f;
  const float* xcol = x + (size_t)b * D * K + j0 + t;
#pragma unroll 8
  for (int c = 0; c < D; ++c) {
    const float xv = xcol[(size_t)c * K];
    const float4 w0 = *(const float4*)&sw2[c][0];
    const float4 w1 = *(const float4*)&sw2[c][4];
    acc[0] = fmaf(xv, w0.x, acc[0]);
    acc[1] = fmaf(xv, w0.y, acc[1]);
    acc[2] = fmaf(xv, w0.z, acc[2]);
    acc[3] = fmaf(xv, w0.w, acc[3]);
    acc[4] = fmaf(xv, w1.x, acc[4]);
    acc[5] = fmaf(xv, w1.y, acc[5]);
    acc[6] = fmaf(xv, w1.z, acc[6]);
    acc[7] = fmaf(xv, w1.w, acc[7]);
  }
#pragma unroll
  for (int u = 0; u < 8; ++u) {
    const float ue = 0.8f * fabsf(a[e0 + u]);
    Rt[((size_t)b * D + e0 + u) * K + j0 + t] = ue * acc[u];
  }
}

// ---------------- K2: per block = (8 i-rows, all 512 j), 512 threads.
// e_ij = 0.25*(SLh_i + SRh_j) + sum_d s_d*relu(Lhat[d][i]+Rhat[d][j]) + bias
// (exact rewrite of sum_d a_d*lrelu(L+R): lrelu(p)=0.2p+0.8relu(p), 0.8|a|
//  folded into Lhat/Rhat, rank-1 part precomputed).
__global__ __launch_bounds__(512) void gat_attn2(
    const float* __restrict__ x, const float* __restrict__ lin_w,
    const float* __restrict__ lin_b, const float* __restrict__ a,
    const float* __restrict__ bias, const float* __restrict__ Rt,
    float* __restrict__ out) {
  const int i0 = blockIdx.x * TI;
  const int b = blockIdx.y;
  const int t = threadIdx.x;

  __shared__ float sxt[D][TI];    // x[b][c][i0+ii] (also residual at the end)
  __shared__ float sLhat[D][TI];  // 0.8|a_d| * L[i][d]
  __shared__ float ssign[D];
  __shared__ float sSLh[TI];
  __shared__ float spart[64];
  __shared__ float seT[TI][K];  // scores -> attn (column-major: conflict-free)

  // ---- Phase A: stage xt tile ----
#pragma unroll
  for (int r = 0; r < 2; ++r) {
    const int idx = r * 512 + t;
    sxt[idx >> 3][idx & 7] = x[((size_t)b * D + (idx >> 3)) * K + i0 + (idx & 7)];
  }
  if (t < D) ssign[t] = (a[t] >= 0.f) ? 1.f : -1.f;
  __syncthreads();

  // ---- Phase B: Lhat[d][ii]; thread = (e, i-pair) ----
  {
    const int e = t & (D - 1);
    const int ig = t >> 7;  // 0..3 -> i-pair (2ig, 2ig+1)
    float l0 = 0.f, l1 = 0.f;
    const float* w1p = lin_w + e;
#pragma unroll 8
    for (int c = 0; c < D; ++c) {
      const float w = w1p[(size_t)c * D];
      const float2 xv = *(const float2*)&sxt[c][2 * ig];
      l0 = fmaf(xv.x, w, l0);
      l1 = fmaf(xv.y, w, l1);
    }
    const float ue = 0.8f * fabsf(a[e]);
    const float bv = lin_b[e];
    sLhat[e][2 * ig] = ue * (l0 + bv);
    sLhat[e][2 * ig + 1] = ue * (l1 + bv);
  }
  __syncthreads();
  if (t < 64) {  // SLh_i = sum_d s_d*Lhat[d][i], split 8 segments
    const int ii = t >> 3, seg = t & 7;
    float p = 0.f;
#pragma unroll
    for (int d = seg * 16; d < seg * 16 + 16; ++d)
      p = fmaf(ssign[d], sLhat[d][ii], p);
    spart[t] = p;
  }
  __syncthreads();
  if (t < TI) {
    float s = 0.f;
#pragma unroll
    for (int g = 0; g < 8; ++g) s += spart[t * 8 + g];
    sSLh[t] = s;
  }
  __syncthreads();

  // ---- Phase C: scores; thread = j ----
  {
    float acc[8];
#pragma unroll
    for (int ii = 0; ii < 8; ++ii) acc[ii] = 0.f;
    float sR = 0.f;
    const float* rcol = Rt + (size_t)b * D * K + t;
#pragma unroll 4
    for (int d = 0; d < D; ++d) {
      const float rv = rcol[(size_t)d * K];
      const float sg = ssign[d];
      float lh[8];
      *(float4*)&lh[0] = *(const float4*)&sLhat[d][0];
      *(float4*)&lh[4] = *(const float4*)&sLhat[d][4];
      sR = fmaf(sg, rv, sR);
#pragma unroll
      for (int ii = 0; ii < 8; ++ii) {
        const float p = lh[ii] + rv;
        acc[ii] = fmaf(sg, fmaxf(p, 0.f), acc[ii]);
      }
    }
#pragma unroll
    for (int ii = 0; ii < 8; ++ii)
      seT[ii][t] = acc[ii] + 0.25f * (sSLh[ii] + sR) +
                   bias[(size_t)(i0 + ii) * K + t];
  }
  __syncthreads();

  // ---- Phase D: softmax over j; wave w owns row ii=w ----
  {
    const int w = t >> 6, lane = t & 63;
    float v[8];
    float m = -1e30f;
#pragma unroll
    for (int q = 0; q < 8; ++q) {
      v[q] = seT[w][lane + 64 * q];
      m = fmaxf(m, v[q]);
    }
#pragma unroll
    for (int off = 32; off > 0; off >>= 1) m = fmaxf(m, __shfl_xor(m, off, 64));
    float s = 0.f;
#pragma unroll
    for (int q = 0; q < 8; ++q) {
      v[q] = __expf(v[q] - m);
      s += v[q];
    }
#pragma unroll
    for (int off = 32; off > 0; off >>= 1) s += __shfl_xor(s, off, 64);
    const float inv = 1.f / s;
#pragma unroll
    for (int q = 0; q < 8; ++q) seT[w][lane + 64 * q] = v[q] * inv;
  }
  __syncthreads();

  // ---- Phase E: agg + sigmoid + residual; thread = (d, j-interleave) ----
  {
    const int dg = t >> 2, jg = t & 3;
    float ag[8];
#pragma unroll
    for (int ii = 0; ii < 8; ++ii) ag[ii] = 0.f;
    const float4* xr = (const float4*)(x + ((size_t)b * D + dg) * K);
#pragma unroll 2
    for (int q = 0; q < 32; ++q) {
      const int chunk = q * 4 + jg;
      const float4 xv = xr[chunk];
#pragma unroll
      for (int ii = 0; ii < 8; ++ii) {
        const float4 av = ((const float4*)&seT[ii][0])[chunk];
        ag[ii] = fmaf(av.x, xv.x, ag[ii]);
        ag[ii] = fmaf(av.y, xv.y, ag[ii]);
        ag[ii] = fmaf(av.z, xv.z, ag[ii]);
        ag[ii] = fmaf(av.w, xv.w, ag[ii]);
      }
    }
#pragma unroll
    for (int ii = 0; ii < 8; ++ii) {
      ag[ii] += __shfl_xor(ag[ii], 1, 64);
      ag[ii] += __shfl_xor(ag[ii], 2, 64);
    }
#pragma unroll
    for (int r = 0; r < 2; ++r) {
      const int ii = jg + 4 * r;
      const float sg = 1.f / (1.f + __expf(-ag[ii]));
      out[((size_t)b * D + dg) * K + i0 + ii] = sg + sxt[dg][ii];
    }
  }
}

// ---------------- Fallback (ws too small): fused, ws-free (proven path kept) --
#define ALPHA 0.2f
__global__ __launch_bounds__(512) void gat_fused(
    const float* __restrict__ x, const float* __restrict__ lin_w,
    const float* __restrict__ lin_b, const float* __restrict__ a,
    const float* __restrict__ bias, float* __restrict__ out) {
  const int i = blockIdx.x, b = blockIdx.y, t = threadIdx.x;
  __shared__ float sxi[D], sLi[D], sa[D];
  __shared__ float lpart[4 * D];
  __shared__ float xtT[D * 64];
  __shared__ float epars[8 * 64];
  __shared__ float se[K];
  __shared__ float sattn[K], spart[K];
  __shared__ float sred[8];

  if (t < D) {
    sxi[t] = x[((size_t)b * D + t) * K + i];
    sa[t] = a[t];
  }
  __syncthreads();
  {
    const int c = t & (D - 1), q = t >> 7;
    float acc = 0.f;
    const float* W1 = lin_w + c;
#pragma unroll 8
    for (int d = q * 32; d < q * 32 + 32; ++d)
      acc = fmaf(sxi[d], W1[(size_t)d * D], acc);
    lpart[q * D + c] = acc;
  }
  __syncthreads();
  if (t < D)
    sLi[t] = lin_b[t] + lpart[t] + lpart[D + t] + lpart[2 * D + t] +
             lpart[3 * D + t];
  __syncthreads();

  for (int jt = 0; jt < K / 64; ++jt) {
    const int j0 = jt * 64;
    for (int idx = t; idx < D * 64; idx += 512)
      xtT[idx] = x[((size_t)b * D + (idx >> 6)) * K + j0 + (idx & 63)];
    __syncthreads();
    const int jj = t & 63, g = t >> 6, dp0 = g * 16;
    float accv[16];
#pragma unroll
    for (int v = 0; v < 16; ++v) accv[v] = 0.f;
    for (int dc = 0; dc < D; dc += 16) {
      float xv[16];
#pragma unroll
      for (int u = 0; u < 16; ++u) xv[u] = xtT[(dc + u) * 64 + jj];
#pragma unroll
      for (int u = 0; u < 16; ++u) {
        const float* W2r = lin_w + (size_t)(D + dc + u) * D + dp0;
#pragma unroll
        for (int v = 0; v < 16; ++v) accv[v] = fmaf(xv[u], W2r[v], accv[v]);
      }
    }
    float ep = 0.f;
#pragma unroll
    for (int v = 0; v < 16; ++v) {
      const float pre = sLi[dp0 + v] + accv[v];
      ep = fmaf(sa[dp0 + v], pre > 0.f ? pre : ALPHA * pre, ep);
    }
    epars[g * 64 + jj] = ep;
    __syncthreads();
    if (t < 64) {
      float esum = bias[(size_t)i * K + j0 + t];
#pragma unroll
      for (int g2 = 0; g2 < 8; ++g2) esum += epars[g2 * 64 + t];
      se[j0 + t] = esum;
    }
    __syncthreads();
  }

  float e = se[t];
  float m = e;
#pragma unroll
  for (int off = 32; off > 0; off >>= 1) m = fmaxf(m, __shfl_xor(m, off, 64));
  if ((t & 63) == 0) sred[t >> 6] = m;
  __syncthreads();
  m = sred[0];
#pragma unroll
  for (int w = 1; w < 8; ++w) m = fmaxf(m, sred[w]);
  const float ev = __expf(e - m);
  float s = ev;
#pragma unroll
  for (int off = 32; off > 0; off >>= 1) s += __shfl_xor(s, off, 64);
  __syncthreads();
  if ((t & 63) == 0) sred[t >> 6] = s;
  __syncthreads();
  s = 0.f;
#pragma unroll
  for (int w = 0; w < 8; ++w) s += sred[w];
  sattn[t] = ev * (1.f / s);
  __syncthreads();

  const int d = t >> 2, c = t & 3;
  const float4* X4 = (const float4*)(x + ((size_t)b * D + d) * K);
  const float4* A4 = (const float4*)sattn;
  float p = 0.f;
#pragma unroll 4
  for (int q = 0; q < K / 16; ++q) {
    const int idx = c + 4 * q;
    float4 xv = X4[idx], av = A4[idx];
    p = fmaf(av.x, xv.x, p);
    p = fmaf(av.y, xv.y, p);
    p = fmaf(av.z, xv.z, p);
    p = fmaf(av.w, xv.w, p);
  }
  spart[t] = p;
  __syncthreads();
  if (t < D) {
    const float agg =
        spart[4 * t] + spart[4 * t + 1] + spart[4 * t + 2] + spart[4 * t + 3];
    const float sg = 1.f / (1.f + __expf(-agg));
    out[((size_t)b * D + t) * K + i] = sg + sxi[t];
  }
}

extern "C" void kernel_launch(void* const* d_in, const int* in_sizes, int n_in,
                              void* d_out, int out_size, void* d_ws,
                              size_t ws_size, hipStream_t stream) {
  const float* x = (const float*)d_in[0];
  const float* lin_w = (const float*)d_in[1];
  const float* lin_b = (const float*)d_in[2];
  const float* a = (const float*)d_in[3];
  const float* bias = (const float*)d_in[4];
  float* out = (float*)d_out;

  const size_t need = (size_t)B * K * D * sizeof(float);  // 1 MB
  if (ws_size >= need && d_ws != nullptr) {
    float* Rt = (float*)d_ws;
    gat_rhat<<<dim3(K / 128, D / 8, B), 128, 0, stream>>>(x, lin_w, a, Rt);
    gat_attn2<<<dim3(K / TI, B), 512, 0, stream>>>(x, lin_w, lin_b, a, bias,
                                                   Rt, out);
  } else {
    gat_fused<<<dim3(K, B), 512, 0, stream>>>(x, lin_w, lin_b, a, bias, out);
  }
}

// Round 6
// 87.030 us; speedup vs baseline: 1.3177x; 1.1315x over previous
//
#include <hip/hip_runtime.h>

#define B 4
#define D 128
#define K 512
#define TI 4

typedef __fp16 h2v __attribute__((ext_vector_type(2)));

__device__ __forceinline__ unsigned pkrtz(float a, float b) {
  h2v h = __builtin_amdgcn_cvt_pkrtz(a, b);
  union { h2v h; unsigned u; } c; c.h = h; return c.u;
}
__device__ __forceinline__ h2v u2h(unsigned u) {
  union { unsigned u; h2v h; } c; c.u = u; return c.h;
}
__device__ __forceinline__ float fdot2f(h2v a, h2v b, float c) {
#if __has_builtin(__builtin_amdgcn_fdot2)
  return __builtin_amdgcn_fdot2(a, b, c, false);
#else
  return c + (float)a.x * (float)b.x + (float)a.y * (float)b.y;
#endif
}
__device__ __forceinline__ h2v relu2(h2v a) {
#if __has_builtin(__builtin_elementwise_max)
  const h2v z = {(__fp16)0.f, (__fp16)0.f};
  return __builtin_elementwise_max(a, z);  // v_pk_max_f16
#else
  h2v r;
  r.x = (float)a.x > 0.f ? a.x : (__fp16)0.f;
  r.y = (float)a.y > 0.f ? a.y : (__fp16)0.f;
  return r;
#endif
}

// ---------------- K1: Lhat^T and Rhat^T, f16-packed over d-pairs ----------
// Lhat[e][i] = 0.8|a_e| * (xt[i]@W1[:,e] + lin_b[e]); Rhat[e][j] = 0.8|a_e| *
// (xt[j]@W2[:,e]).  Stored as half2 (e-pair) per dword: [b][e/2][pos].
// Grid (K/64, D/16, B) = 256 blocks x 256 thr (4 waves).
__global__ __launch_bounds__(256) void gat_lr16(
    const float* __restrict__ x, const float* __restrict__ lin_w,
    const float* __restrict__ lin_b, const float* __restrict__ a,
    unsigned* __restrict__ LhT, unsigned* __restrict__ RhT) {
  const int j0 = blockIdx.x * 64;
  const int E0 = blockIdx.y * 16;
  const int b = blockIdx.z;
  const int t = threadIdx.x;
  __shared__ float sx[D][64];    // 32 KB x-tile
  __shared__ float sw1[D][16];   // 8 KB W1 slab
  __shared__ float sw2[D][16];   // 8 KB W2 slab
#pragma unroll
  for (int r = 0; r < 8; ++r) {  // x-tile: 2048 float4s
    const int fid = t + 256 * r;
    const int row = fid >> 4, c4 = fid & 15;
    *(float4*)&sx[row][4 * c4] =
        *(const float4*)&x[((size_t)b * D + row) * K + j0 + 4 * c4];
  }
#pragma unroll
  for (int r = 0; r < 8; ++r) {  // W slabs: 2048 dwords each
    const int idx = t + 256 * r;
    const int row = idx >> 4, e = idx & 15;
    sw1[row][e] = lin_w[(size_t)row * D + E0 + e];
    sw2[row][e] = lin_w[(size_t)(D + row) * D + E0 + e];
  }
  __syncthreads();
  const int j = t & 63, g = t >> 6;  // wave g owns e-quad E0+4g..+3
  float accL[4] = {0.f, 0.f, 0.f, 0.f}, accR[4] = {0.f, 0.f, 0.f, 0.f};
#pragma unroll 8
  for (int c = 0; c < D; ++c) {
    const float xv = sx[c][j];
    const float4 w1 = *(const float4*)&sw1[c][4 * g];
    const float4 w2 = *(const float4*)&sw2[c][4 * g];
    accL[0] = fmaf(xv, w1.x, accL[0]);
    accL[1] = fmaf(xv, w1.y, accL[1]);
    accL[2] = fmaf(xv, w1.z, accL[2]);
    accL[3] = fmaf(xv, w1.w, accL[3]);
    accR[0] = fmaf(xv, w2.x, accR[0]);
    accR[1] = fmaf(xv, w2.y, accR[1]);
    accR[2] = fmaf(xv, w2.z, accR[2]);
    accR[3] = fmaf(xv, w2.w, accR[3]);
  }
  const int e0 = E0 + 4 * g;
#pragma unroll
  for (int u = 0; u < 2; ++u) {
    const int ea = e0 + 2 * u, eb = ea + 1;
    const float uea = 0.8f * fabsf(a[ea]), ueb = 0.8f * fabsf(a[eb]);
    const float La = uea * (accL[2 * u] + lin_b[ea]);
    const float Lb = ueb * (accL[2 * u + 1] + lin_b[eb]);
    const float Ra = uea * accR[2 * u];
    const float Rb = ueb * accR[2 * u + 1];
    const size_t dp = (size_t)(ea >> 1);
    LhT[((size_t)b * (D / 2) + dp) * K + j0 + j] = pkrtz(La, Lb);
    RhT[((size_t)b * (D / 2) + dp) * K + j0 + j] = pkrtz(Ra, Rb);
  }
}

// ---------------- K2: scores (f16 pk core) + softmax + agg + epilogue ------
// e_ij = 0.25*(SLh_i + SRh_j) + sum_dp dot2(s2, relu(lh2+rv2)) + bias.
// Grid (K/TI, B) = 512 blocks x 256 thr (4 waves); each thread 2 j's.
__global__ __launch_bounds__(256) void gat_attn16(
    const float* __restrict__ x, const float* __restrict__ a,
    const float* __restrict__ bias, const unsigned* __restrict__ LhT,
    const unsigned* __restrict__ RhT, float* __restrict__ out) {
  const int i0 = blockIdx.x * TI;
  const int b = blockIdx.y;
  const int t = threadIdx.x;
  __shared__ float sxt[D][TI];      // residual tile
  __shared__ unsigned slh[D / 2][TI];
  __shared__ unsigned ssg[D / 2];
  __shared__ float sSL[TI];
  __shared__ float seT[TI][K];      // scores -> attn

  // ---- A: stage tiles ----
  {
    int idx = t;
    sxt[idx >> 2][idx & 3] = x[((size_t)b * D + (idx >> 2)) * K + i0 + (idx & 3)];
    idx = t + 256;
    sxt[idx >> 2][idx & 3] = x[((size_t)b * D + (idx >> 2)) * K + i0 + (idx & 3)];
    const int dp = t >> 2, ii = t & 3;
    slh[dp][ii] = LhT[((size_t)b * (D / 2) + dp) * K + i0 + ii];
    if (t < D / 2) {
      const float s0 = (a[2 * t] >= 0.f) ? 1.f : -1.f;
      const float s1 = (a[2 * t + 1] >= 0.f) ? 1.f : -1.f;
      ssg[t] = pkrtz(s0, s1);
    }
  }
  __syncthreads();
  // ---- SLh_i: wave w reduces row ii=w ----
  {
    const int ii = t >> 6, dp = t & 63;
    float v = fdot2f(u2h(ssg[dp]), u2h(slh[dp][ii]), 0.f);
#pragma unroll
    for (int off = 32; off > 0; off >>= 1) v += __shfl_xor(v, off, 64);
    if ((t & 63) == 0) sSL[ii] = v;
  }
  __syncthreads();

  // ---- C: scores for jA=t, jB=t+256 ----
  {
    const unsigned* rc = RhT + (size_t)b * (D / 2) * K;
    float accA[4] = {0.f, 0.f, 0.f, 0.f}, accB[4] = {0.f, 0.f, 0.f, 0.f};
    float srA = 0.f, srB = 0.f;
#pragma unroll 4
    for (int dp = 0; dp < D / 2; ++dp) {
      const unsigned ra = rc[(size_t)dp * K + t];
      const unsigned rb = rc[(size_t)dp * K + t + 256];
      const uint4 lh4 = *(const uint4*)&slh[dp][0];
      const h2v s2 = u2h(ssg[dp]);
      const h2v rva = u2h(ra), rvb = u2h(rb);
      srA = fdot2f(s2, rva, srA);
      srB = fdot2f(s2, rvb, srB);
      h2v l;
      l = u2h(lh4.x);
      accA[0] = fdot2f(s2, relu2(l + rva), accA[0]);
      accB[0] = fdot2f(s2, relu2(l + rvb), accB[0]);
      l = u2h(lh4.y);
      accA[1] = fdot2f(s2, relu2(l + rva), accA[1]);
      accB[1] = fdot2f(s2, relu2(l + rvb), accB[1]);
      l = u2h(lh4.z);
      accA[2] = fdot2f(s2, relu2(l + rva), accA[2]);
      accB[2] = fdot2f(s2, relu2(l + rvb), accB[2]);
      l = u2h(lh4.w);
      accA[3] = fdot2f(s2, relu2(l + rva), accA[3]);
      accB[3] = fdot2f(s2, relu2(l + rvb), accB[3]);
    }
#pragma unroll
    for (int ii = 0; ii < TI; ++ii) {
      seT[ii][t] = accA[ii] + 0.25f * (sSL[ii] + srA) +
                   bias[(size_t)(i0 + ii) * K + t];
      seT[ii][t + 256] = accB[ii] + 0.25f * (sSL[ii] + srB) +
                         bias[(size_t)(i0 + ii) * K + t + 256];
    }
  }
  __syncthreads();

  // ---- D: softmax; wave w owns row w ----
  {
    const int w = t >> 6, lane = t & 63;
    float v[8];
    float m = -1e30f;
#pragma unroll
    for (int q = 0; q < 8; ++q) {
      v[q] = seT[w][lane + 64 * q];
      m = fmaxf(m, v[q]);
    }
#pragma unroll
    for (int off = 32; off > 0; off >>= 1) m = fmaxf(m, __shfl_xor(m, off, 64));
    float s = 0.f;
#pragma unroll
    for (int q = 0; q < 8; ++q) {
      v[q] = __expf(v[q] - m);
      s += v[q];
    }
#pragma unroll
    for (int off = 32; off > 0; off >>= 1) s += __shfl_xor(s, off, 64);
    const float inv = 1.f / s;
#pragma unroll
    for (int q = 0; q < 8; ++q) seT[w][lane + 64 * q] = v[q] * inv;
  }
  __syncthreads();

  // ---- E: agg + sigmoid + residual; thread = (dg = t>>1, jg = t&1) ----
  {
    const int dg = t >> 1, jg = t & 1;
    float ag[4] = {0.f, 0.f, 0.f, 0.f};
    const float4* xr = (const float4*)(x + ((size_t)b * D + dg) * K);
#pragma unroll 4
    for (int q = 0; q < 64; ++q) {
      const int chunk = 2 * q + jg;
      const float4 xv = xr[chunk];
#pragma unroll
      for (int ii = 0; ii < TI; ++ii) {
        const float4 av = ((const float4*)&seT[ii][0])[chunk];
        ag[ii] = fmaf(av.x, xv.x, ag[ii]);
        ag[ii] = fmaf(av.y, xv.y, ag[ii]);
        ag[ii] = fmaf(av.z, xv.z, ag[ii]);
        ag[ii] = fmaf(av.w, xv.w, ag[ii]);
      }
    }
#pragma unroll
    for (int ii = 0; ii < TI; ++ii) ag[ii] += __shfl_xor(ag[ii], 1, 64);
    if (jg == 0) {
#pragma unroll
      for (int ii = 0; ii < TI; ++ii) {
        const float sg = 1.f / (1.f + __expf(-ag[ii]));
        out[((size_t)b * D + dg) * K + i0 + ii] = sg + sxt[dg][ii];
      }
    }
  }
}

// ---------------- Fallback (ws too small): fused, ws-free ----------------
#define ALPHA 0.2f
__global__ __launch_bounds__(512) void gat_fused(
    const float* __restrict__ x, const float* __restrict__ lin_w,
    const float* __restrict__ lin_b, const float* __restrict__ a,
    const float* __restrict__ bias, float* __restrict__ out) {
  const int i = blockIdx.x, b = blockIdx.y, t = threadIdx.x;
  __shared__ float sxi[D], sLi[D], sa[D];
  __shared__ float lpart[4 * D];
  __shared__ float xtT[D * 64];
  __shared__ float epars[8 * 64];
  __shared__ float se[K];
  __shared__ float sattn[K], spart[K];
  __shared__ float sred[8];

  if (t < D) {
    sxi[t] = x[((size_t)b * D + t) * K + i];
    sa[t] = a[t];
  }
  __syncthreads();
  {
    const int c = t & (D - 1), q = t >> 7;
    float acc = 0.f;
    const float* W1 = lin_w + c;
#pragma unroll 8
    for (int d = q * 32; d < q * 32 + 32; ++d)
      acc = fmaf(sxi[d], W1[(size_t)d * D], acc);
    lpart[q * D + c] = acc;
  }
  __syncthreads();
  if (t < D)
    sLi[t] = lin_b[t] + lpart[t] + lpart[D + t] + lpart[2 * D + t] +
             lpart[3 * D + t];
  __syncthreads();

  for (int jt = 0; jt < K / 64; ++jt) {
    const int j0 = jt * 64;
    for (int idx = t; idx < D * 64; idx += 512)
      xtT[idx] = x[((size_t)b * D + (idx >> 6)) * K + j0 + (idx & 63)];
    __syncthreads();
    const int jj = t & 63, g = t >> 6, dp0 = g * 16;
    float accv[16];
#pragma unroll
    for (int v = 0; v < 16; ++v) accv[v] = 0.f;
    for (int dc = 0; dc < D; dc += 16) {
      float xv[16];
#pragma unroll
      for (int u = 0; u < 16; ++u) xv[u] = xtT[(dc + u) * 64 + jj];
#pragma unroll
      for (int u = 0; u < 16; ++u) {
        const float* W2r = lin_w + (size_t)(D + dc + u) * D + dp0;
#pragma unroll
        for (int v = 0; v < 16; ++v) accv[v] = fmaf(xv[u], W2r[v], accv[v]);
      }
    }
    float ep = 0.f;
#pragma unroll
    for (int v = 0; v < 16; ++v) {
      const float pre = sLi[dp0 + v] + accv[v];
      ep = fmaf(sa[dp0 + v], pre > 0.f ? pre : ALPHA * pre, ep);
    }
    epars[g * 64 + jj] = ep;
    __syncthreads();
    if (t < 64) {
      float esum = bias[(size_t)i * K + j0 + t];
#pragma unroll
      for (int g2 = 0; g2 < 8; ++g2) esum += epars[g2 * 64 + t];
      se[j0 + t] = esum;
    }
    __syncthreads();
  }

  float e = se[t];
  float m = e;
#pragma unroll
  for (int off = 32; off > 0; off >>= 1) m = fmaxf(m, __shfl_xor(m, off, 64));
  if ((t & 63) == 0) sred[t >> 6] = m;
  __syncthreads();
  m = sred[0];
#pragma unroll
  for (int w = 1; w < 8; ++w) m = fmaxf(m, sred[w]);
  const float ev = __expf(e - m);
  float s = ev;
#pragma unroll
  for (int off = 32; off > 0; off >>= 1) s += __shfl_xor(s, off, 64);
  __syncthreads();
  if ((t & 63) == 0) sred[t >> 6] = s;
  __syncthreads();
  s = 0.f;
#pragma unroll
  for (int w = 0; w < 8; ++w) s += sred[w];
  sattn[t] = ev * (1.f / s);
  __syncthreads();

  const int d = t >> 2, c = t & 3;
  const float4* X4 = (const float4*)(x + ((size_t)b * D + d) * K);
  const float4* A4 = (const float4*)sattn;
  float p = 0.f;
#pragma unroll 4
  for (int q = 0; q < K / 16; ++q) {
    const int idx = c + 4 * q;
    float4 xv = X4[idx], av = A4[idx];
    p = fmaf(av.x, xv.x, p);
    p = fmaf(av.y, xv.y, p);
    p = fmaf(av.z, xv.z, p);
    p = fmaf(av.w, xv.w, p);
  }
  spart[t] = p;
  __syncthreads();
  if (t < D) {
    const float agg =
        spart[4 * t] + spart[4 * t + 1] + spart[4 * t + 2] + spart[4 * t + 3];
    const float sg = 1.f / (1.f + __expf(-agg));
    out[((size_t)b * D + t) * K + i] = sg + sxi[t];
  }
}

extern "C" void kernel_launch(void* const* d_in, const int* in_sizes, int n_in,
                              void* d_out, int out_size, void* d_ws,
                              size_t ws_size, hipStream_t stream) {
  const float* x = (const float*)d_in[0];
  const float* lin_w = (const float*)d_in[1];
  const float* lin_b = (const float*)d_in[2];
  const float* a = (const float*)d_in[3];
  const float* bias = (const float*)d_in[4];
  float* out = (float*)d_out;

  const size_t half_words = (size_t)B * (D / 2) * K;  // 512 KB each
  const size_t need = 2 * half_words * sizeof(unsigned);
  if (ws_size >= need && d_ws != nullptr) {
    unsigned* LhT = (unsigned*)d_ws;
    unsigned* RhT = LhT + half_words;
    gat_lr16<<<dim3(K / 64, D / 16, B), 256, 0, stream>>>(x, lin_w, lin_b, a,
                                                          LhT, RhT);
    gat_attn16<<<dim3(K / TI, B), 256, 0, stream>>>(x, a, bias, LhT, RhT, out);
  } else {
    gat_fused<<<dim3(K, B), 512, 0, stream>>>(x, lin_w, lin_b, a, bias, out);
  }
}